// Round 1
// baseline (266.602 us; speedup 1.0000x reference)
//
#include <hip/hip_runtime.h>
#include <cstdint>
#include <cstddef>

// Problem constants
#define D_MODEL  1024
#define N_ASSETS 4096
#define BATCH    64

typedef __attribute__((ext_vector_type(8))) short short8_t;  // 8 bf16 (4 VGPRs)
typedef __attribute__((ext_vector_type(4))) float floatx4;

__device__ __forceinline__ unsigned short f2bf(float x){
  // round-to-nearest-even fp32 -> bf16
  unsigned int u = __float_as_uint(x);
  return (unsigned short)((u + 0x7FFFu + ((u >> 16) & 1u)) >> 16);
}

__device__ __forceinline__ float gelu_f(float x){
  // tanh-form GELU: x * sigmoid(1.595769f * x * (1 + 0.044715 x^2))
  // exp2 constant = 1.5957691 * log2(e) = 2.3022082
  float x2 = x * x;
  float p  = x * (0.044715f * x2 + 1.0f);
  float e  = __builtin_amdgcn_exp2f(-2.3022082f * p);
  return x * __builtin_amdgcn_rcpf(e + 1.0f);
}

// ---------- P1: asset_emb fp32 -> bf16 ----------
__global__ void k_cvt_ae(const float* __restrict__ ae, unsigned short* __restrict__ out){
  int idx = blockIdx.x * 256 + threadIdx.x;           // 1024 blocks * 256 thr
  #pragma unroll
  for (int i = 0; i < 4; ++i){
    int f = idx + i * 262144;                          // 1,048,576 float4 total
    float4 v = ((const float4*)ae)[f];
    ushort4 o;
    o.x = f2bf(v.x); o.y = f2bf(v.y); o.z = f2bf(v.z); o.w = f2bf(v.w);
    ((ushort4*)out)[f] = o;
  }
}

// ---------- P2: w1 bottom half -> bf16, transposed to [j][k] ----------
__global__ void k_trans_w1(const float* __restrict__ w1, unsigned short* __restrict__ w1t){
  __shared__ float tile[64][65];
  int k0 = blockIdx.x * 64, j0 = blockIdx.y * 64;
  int t = threadIdx.x;
  #pragma unroll
  for (int i = 0; i < 4; ++i){
    int f = t + i * 256;
    int kk = f >> 4, js = (f & 15) * 4;
    float4 v = *(const float4*)&w1[(1024 + k0 + kk) * 1024 + j0 + js];
    tile[kk][js+0] = v.x; tile[kk][js+1] = v.y; tile[kk][js+2] = v.z; tile[kk][js+3] = v.w;
  }
  __syncthreads();
  #pragma unroll
  for (int i = 0; i < 4; ++i){
    int f = t + i * 256;
    int jj = f >> 4, ks = (f & 15) * 4;
    ushort4 o;
    o.x = f2bf(tile[ks+0][jj]); o.y = f2bf(tile[ks+1][jj]);
    o.z = f2bf(tile[ks+2][jj]); o.w = f2bf(tile[ks+3][jj]);
    *(ushort4*)&w1t[(j0 + jj) * 1024 + k0 + ks] = o;
  }
}

// ---------- K1: sp = s@bilinear_w, hs = s@w1[:d]  (fp32, split-K atomics) ----------
// grid (32 j-tiles of 64, 8 k-chunks of 128), 256 threads
__global__ void k_small_gemm(const float* __restrict__ s, const float* __restrict__ bw,
                             const float* __restrict__ w1, float* __restrict__ sp,
                             float* __restrict__ hs){
  int j0g = blockIdx.x * 64;
  int k0  = blockIdx.y * 128;
  const float* Wp; float* outp; int jcol;
  if (j0g < 1024){ Wp = bw; outp = sp; jcol = j0g; }
  else           { Wp = w1; outp = hs; jcol = j0g - 1024; }
  int t = threadIdx.x;
  int tb = t >> 3, tj = t & 7;
  int b0 = tb * 2;
  const float* s0p = s + b0 * 1024;
  const float* s1p = s0p + 1024;
  float a0[4] = {0,0,0,0}, a1[4] = {0,0,0,0}, c0[4] = {0,0,0,0}, c1[4] = {0,0,0,0};
  #pragma unroll 4
  for (int kk = 0; kk < 128; ++kk){
    int k = k0 + kk;
    float sv0 = s0p[k], sv1 = s1p[k];
    const float* wr = Wp + k * 1024 + jcol;
    float4 wA = *(const float4*)&wr[tj * 4];
    float4 wB = *(const float4*)&wr[32 + tj * 4];
    a0[0] += sv0 * wA.x; a0[1] += sv0 * wA.y; a0[2] += sv0 * wA.z; a0[3] += sv0 * wA.w;
    a1[0] += sv1 * wA.x; a1[1] += sv1 * wA.y; a1[2] += sv1 * wA.z; a1[3] += sv1 * wA.w;
    c0[0] += sv0 * wB.x; c0[1] += sv0 * wB.y; c0[2] += sv0 * wB.z; c0[3] += sv0 * wB.w;
    c1[0] += sv1 * wB.x; c1[1] += sv1 * wB.y; c1[2] += sv1 * wB.z; c1[3] += sv1 * wB.w;
  }
  float* oA = outp + b0 * 1024 + jcol + tj * 4;
  float* oB = oA + 32;
  #pragma unroll
  for (int u = 0; u < 4; ++u){
    atomicAdd(&oA[u],        a0[u]);
    atomicAdd(&oA[u + 1024], a1[u]);
    atomicAdd(&oB[u],        c0[u]);
    atomicAdd(&oB[u + 1024], c1[u]);
  }
}

// ---------- K2: ha = asset_emb @ w1[d:] + b1  (bf16 MFMA, fp32 out) ----------
// grid (8 n-blocks, 32 m-blocks), 512 threads (8 waves), tile 128x128
__launch_bounds__(512)
__global__ void k_mfma_ha(const unsigned short* __restrict__ aeb,
                          const unsigned short* __restrict__ w1t,
                          const float* __restrict__ b1, float* __restrict__ ha){
  __shared__ unsigned short At[128 * 32];   // [m][k] bf16
  __shared__ unsigned short Bt[128 * 32];   // [n][k] bf16 (already transposed globally)
  int t = threadIdx.x;
  int w = t >> 6, lane = t & 63;
  int wm = w >> 2, wn = w & 3;              // 2 x 4 wave grid -> 64m x 32n per wave
  int lm = lane & 15, quad = lane >> 4;
  int m0g = blockIdx.y * 128, n0g = blockIdx.x * 128;
  floatx4 acc[4][2];
  #pragma unroll
  for (int mi = 0; mi < 4; ++mi)
    #pragma unroll
    for (int ni = 0; ni < 2; ++ni)
      acc[mi][ni] = (floatx4)(0.0f);
  const unsigned short* Ab = aeb + (size_t)m0g * 1024;
  const unsigned short* Bb = w1t + (size_t)n0g * 1024;
  int r = t >> 2, seg = (t & 3) * 8;        // 128 rows, 4 x 8 bf16 segs
  for (int k0 = 0; k0 < 1024; k0 += 32){
    int4 va = *(const int4*)(Ab + (size_t)r * 1024 + k0 + seg);
    int4 vb = *(const int4*)(Bb + (size_t)r * 1024 + k0 + seg);
    ((int4*)At)[t] = va;
    ((int4*)Bt)[t] = vb;
    __syncthreads();
    short8_t a[4], b[2];
    #pragma unroll
    for (int mi = 0; mi < 4; ++mi)
      a[mi] = *(const short8_t*)&At[(wm * 64 + mi * 16 + lm) * 32 + quad * 8];
    #pragma unroll
    for (int ni = 0; ni < 2; ++ni)
      b[ni] = *(const short8_t*)&Bt[(wn * 32 + ni * 16 + lm) * 32 + quad * 8];
    #pragma unroll
    for (int mi = 0; mi < 4; ++mi)
      #pragma unroll
      for (int ni = 0; ni < 2; ++ni)
        acc[mi][ni] = __builtin_amdgcn_mfma_f32_16x16x32_bf16(a[mi], b[ni], acc[mi][ni], 0, 0, 0);
    __syncthreads();
  }
  #pragma unroll
  for (int ni = 0; ni < 2; ++ni){
    int n = n0g + wn * 32 + ni * 16 + lm;   // C/D: col = lane&15
    float b1v = b1[n];
    #pragma unroll
    for (int mi = 0; mi < 4; ++mi){
      int mb = m0g + wm * 64 + mi * 16 + quad * 4;   // row = quad*4 + reg
      #pragma unroll
      for (int rr = 0; rr < 4; ++rr)
        ha[(size_t)(mb + rr) * 1024 + n] = acc[mi][ni][rr] + b1v;
    }
  }
}

// ---------- K3: scores[b][n] = sum_d( gelu(hs+ha)*w2 + sp*ae ) ----------
// grid (256 n-tiles of 16, 4 b-tiles of 16), 128 threads; 2 elems/thread
__launch_bounds__(128)
__global__ void k_fused(const float* __restrict__ ha, const float* __restrict__ ae,
                        const float* __restrict__ hs, const float* __restrict__ sp,
                        const float* __restrict__ w2, float* __restrict__ scores){
  __shared__ float ha_t[32][18];   // [d][n]
  __shared__ float ae_t[32][18];
  __shared__ float hs_t[32][18];   // [d][b]
  __shared__ float sp_t[32][18];
  __shared__ float w2_t[32];
  int n0g = blockIdx.x * 16, b0g = blockIdx.y * 16;
  int t = threadIdx.x;
  int tb = t >> 4, tn = t & 15;
  int b0 = tb * 2;
  int rr = t >> 3, ds = (t & 7) * 4;
  float acc0 = 0.0f, acc1 = 0.0f;
  for (int d0 = 0; d0 < 1024; d0 += 32){
    float4 v;
    v = *(const float4*)&ha[(n0g + rr) * 1024 + d0 + ds];
    ha_t[ds+0][rr] = v.x; ha_t[ds+1][rr] = v.y; ha_t[ds+2][rr] = v.z; ha_t[ds+3][rr] = v.w;
    v = *(const float4*)&ae[(n0g + rr) * 1024 + d0 + ds];
    ae_t[ds+0][rr] = v.x; ae_t[ds+1][rr] = v.y; ae_t[ds+2][rr] = v.z; ae_t[ds+3][rr] = v.w;
    v = *(const float4*)&hs[(b0g + rr) * 1024 + d0 + ds];
    hs_t[ds+0][rr] = v.x; hs_t[ds+1][rr] = v.y; hs_t[ds+2][rr] = v.z; hs_t[ds+3][rr] = v.w;
    v = *(const float4*)&sp[(b0g + rr) * 1024 + d0 + ds];
    sp_t[ds+0][rr] = v.x; sp_t[ds+1][rr] = v.y; sp_t[ds+2][rr] = v.z; sp_t[ds+3][rr] = v.w;
    if (t < 32) w2_t[t] = w2[d0 + t];
    __syncthreads();
    #pragma unroll 8
    for (int dd = 0; dd < 32; ++dd){
      float2 hv = *(const float2*)&hs_t[dd][b0];
      float2 pv = *(const float2*)&sp_t[dd][b0];
      float hav = ha_t[dd][tn];
      float aev = ae_t[dd][tn];
      float wv  = w2_t[dd];
      float h0 = hv.x + hav;
      float h1 = hv.y + hav;
      acc0 += gelu_f(h0) * wv + pv.x * aev;
      acc1 += gelu_f(h1) * wv + pv.y * aev;
    }
    __syncthreads();
  }
  scores[(b0g + b0)     * 4096 + n0g + tn] = acc0;
  scores[(b0g + b0 + 1) * 4096 + n0g + tn] = acc1;
}

// ---------- K4: row softmax ----------
__global__ void k_softmax(const float* __restrict__ scores, float* __restrict__ out){
  int b = blockIdx.x, t = threadIdx.x;
  const float* row = scores + b * 4096;
  float v[16];
  float m = -3.0e38f;
  #pragma unroll
  for (int i = 0; i < 16; ++i){ v[i] = row[t + i * 256]; m = fmaxf(m, v[i]); }
  #pragma unroll
  for (int off = 32; off > 0; off >>= 1) m = fmaxf(m, __shfl_xor(m, off, 64));
  __shared__ float redm[4], reds[4];
  int w = t >> 6, lane = t & 63;
  if (lane == 0) redm[w] = m;
  __syncthreads();
  m = fmaxf(fmaxf(redm[0], redm[1]), fmaxf(redm[2], redm[3]));
  float ssum = 0.0f;
  #pragma unroll
  for (int i = 0; i < 16; ++i){
    float e = __builtin_amdgcn_exp2f((v[i] - m) * 1.4426950f);
    v[i] = e; ssum += e;
  }
  #pragma unroll
  for (int off = 32; off > 0; off >>= 1) ssum += __shfl_xor(ssum, off, 64);
  if (lane == 0) reds[w] = ssum;
  __syncthreads();
  ssum = (reds[0] + reds[1]) + (reds[2] + reds[3]);
  float inv = __builtin_amdgcn_rcpf(ssum);
  #pragma unroll
  for (int i = 0; i < 16; ++i) out[b * 4096 + t + i * 256] = v[i] * inv;
}

extern "C" void kernel_launch(void* const* d_in, const int* in_sizes, int n_in,
                              void* d_out, int out_size, void* d_ws, size_t ws_size,
                              hipStream_t stream){
  (void)in_sizes; (void)n_in; (void)out_size; (void)ws_size;
  const float* ms = (const float*)d_in[0];   // [64,1024]
  const float* ae = (const float*)d_in[1];   // [4096,1024]
  const float* bw = (const float*)d_in[2];   // [1024,1024]
  // d_in[3] bilinear_b: scalar added to every score -> softmax-invariant, skipped
  const float* w1 = (const float*)d_in[4];   // [2048,1024]
  const float* b1 = (const float*)d_in[5];   // [1024]
  const float* w2 = (const float*)d_in[6];   // [1024,1] flat
  // d_in[7] b2: scalar, softmax-invariant, skipped
  float* out = (float*)d_out;

  char* ws = (char*)d_ws;
  float*          sp     = (float*)(ws + 0);          // 256 KB
  float*          hs     = (float*)(ws + 262144);     // 256 KB
  float*          ha     = (float*)(ws + 524288);     // 16 MB
  float*          scores = (float*)(ws + 17301504);   // 1 MB
  unsigned short* aeb    = (unsigned short*)(ws + 18350080);  // 8 MB
  unsigned short* w1t    = (unsigned short*)(ws + 26738688);  // 2 MB

  hipMemsetAsync(sp, 0, 524288, stream);  // zero sp+hs for split-K atomics

  k_cvt_ae    <<<1024, 256, 0, stream>>>(ae, aeb);
  k_trans_w1  <<<dim3(16, 16), 256, 0, stream>>>(w1, w1t);
  k_small_gemm<<<dim3(32, 8), 256, 0, stream>>>(ms, bw, w1, sp, hs);
  k_mfma_ha   <<<dim3(8, 32), 512, 0, stream>>>(aeb, w1t, b1, ha);
  k_fused     <<<dim3(256, 4), 128, 0, stream>>>(ha, ae, hs, sp, w2, scores);
  k_softmax   <<<64, 256, 0, stream>>>(scores, out);
}

// Round 2
// 223.852 us; speedup vs baseline: 1.1910x; 1.1910x over previous
//
#include <hip/hip_runtime.h>
#include <cstdint>
#include <cstddef>

typedef __attribute__((ext_vector_type(8))) short short8_t;  // 8 bf16 (4 VGPRs)
typedef __attribute__((ext_vector_type(4))) float floatx4;

__device__ __forceinline__ unsigned short f2bf(float x){
  unsigned int u = __float_as_uint(x);
  return (unsigned short)((u + 0x7FFFu + ((u >> 16) & 1u)) >> 16);
}

// tanh-form GELU, constant-folded: 6 main-pipe ops + exp2 + rcp
__device__ __forceinline__ float gelu_f(float x){
  float x2 = x * x;
  float t  = __builtin_fmaf(-0.10294293f, x2, -2.3022082f); // -2.3022082*(1+0.044715 x2)
  float a  = x * t;
  float e  = __builtin_amdgcn_exp2f(a);
  return x * __builtin_amdgcn_rcpf(e + 1.0f);
}

__device__ __forceinline__ void gl2lds16(const void* g, void* l){
  __builtin_amdgcn_global_load_lds(
      (const __attribute__((address_space(1))) unsigned int*)g,
      (__attribute__((address_space(3))) unsigned int*)l, 16, 0, 0);
}

// ---------- P1: asset_emb fp32 -> bf16 ----------
__global__ void k_cvt_ae(const float* __restrict__ ae, unsigned short* __restrict__ out){
  int idx = blockIdx.x * 256 + threadIdx.x;
  #pragma unroll
  for (int i = 0; i < 4; ++i){
    int f = idx + i * 262144;
    float4 v = ((const float4*)ae)[f];
    ushort4 o;
    o.x = f2bf(v.x); o.y = f2bf(v.y); o.z = f2bf(v.z); o.w = f2bf(v.w);
    ((ushort4*)out)[f] = o;
  }
}

// ---------- P2: w1 bottom half -> bf16, transposed to [j][k] ----------
__global__ void k_trans_w1(const float* __restrict__ w1, unsigned short* __restrict__ w1t){
  __shared__ float tile[64][65];
  int k0 = blockIdx.x * 64, j0 = blockIdx.y * 64;
  int t = threadIdx.x;
  #pragma unroll
  for (int i = 0; i < 4; ++i){
    int f = t + i * 256;
    int kk = f >> 4, js = (f & 15) * 4;
    float4 v = *(const float4*)&w1[(1024 + k0 + kk) * 1024 + j0 + js];
    tile[kk][js+0] = v.x; tile[kk][js+1] = v.y; tile[kk][js+2] = v.z; tile[kk][js+3] = v.w;
  }
  __syncthreads();
  #pragma unroll
  for (int i = 0; i < 4; ++i){
    int f = t + i * 256;
    int jj = f >> 4, ks = (f & 15) * 4;
    ushort4 o;
    o.x = f2bf(tile[ks+0][jj]); o.y = f2bf(tile[ks+1][jj]);
    o.z = f2bf(tile[ks+2][jj]); o.w = f2bf(tile[ks+3][jj]);
    *(ushort4*)&w1t[(j0 + jj) * 1024 + k0 + ks] = o;
  }
}

// ---------- K1: sp = s@bilinear_w, hs = s@w1[:d]  (fp32, split-K atomics) ----------
__global__ void k_small_gemm(const float* __restrict__ s, const float* __restrict__ bw,
                             const float* __restrict__ w1, float* __restrict__ sp,
                             float* __restrict__ hs){
  int j0g = blockIdx.x * 64;
  int k0  = blockIdx.y * 128;
  const float* Wp; float* outp; int jcol;
  if (j0g < 1024){ Wp = bw; outp = sp; jcol = j0g; }
  else           { Wp = w1; outp = hs; jcol = j0g - 1024; }
  int t = threadIdx.x;
  int tb = t >> 3, tj = t & 7;
  int b0 = tb * 2;
  const float* s0p = s + b0 * 1024;
  const float* s1p = s0p + 1024;
  float a0[4] = {0,0,0,0}, a1[4] = {0,0,0,0}, c0[4] = {0,0,0,0}, c1[4] = {0,0,0,0};
  #pragma unroll 4
  for (int kk = 0; kk < 128; ++kk){
    int k = k0 + kk;
    float sv0 = s0p[k], sv1 = s1p[k];
    const float* wr = Wp + k * 1024 + jcol;
    float4 wA = *(const float4*)&wr[tj * 4];
    float4 wB = *(const float4*)&wr[32 + tj * 4];
    a0[0] += sv0 * wA.x; a0[1] += sv0 * wA.y; a0[2] += sv0 * wA.z; a0[3] += sv0 * wA.w;
    a1[0] += sv1 * wA.x; a1[1] += sv1 * wA.y; a1[2] += sv1 * wA.z; a1[3] += sv1 * wA.w;
    c0[0] += sv0 * wB.x; c0[1] += sv0 * wB.y; c0[2] += sv0 * wB.z; c0[3] += sv0 * wB.w;
    c1[0] += sv1 * wB.x; c1[1] += sv1 * wB.y; c1[2] += sv1 * wB.z; c1[3] += sv1 * wB.w;
  }
  float* oA = outp + b0 * 1024 + jcol + tj * 4;
  float* oB = oA + 32;
  #pragma unroll
  for (int u = 0; u < 4; ++u){
    atomicAdd(&oA[u],        a0[u]);
    atomicAdd(&oA[u + 1024], a1[u]);
    atomicAdd(&oB[u],        c0[u]);
    atomicAdd(&oB[u + 1024], c1[u]);
  }
}

// ---------- K2: ha = asset_emb @ w1[d:] + b1  (bf16 MFMA + global_load_lds) ----------
// grid (16 n-tiles, 32 m-tiles), 256 threads (4 waves), tile 128m x 64n, BK=32
__launch_bounds__(256)
__global__ void k_mfma_ha(const unsigned short* __restrict__ aeb,
                          const unsigned short* __restrict__ w1t,
                          const float* __restrict__ b1, float* __restrict__ ha){
  __shared__ unsigned short At[128 * 32];   // [m][k] bf16, 8 KB
  __shared__ unsigned short Bt[64 * 32];    // [n][k] bf16, 4 KB
  int t = threadIdx.x;
  int w = t >> 6, lane = t & 63;
  int wm = w >> 1, wn = w & 1;              // 2x2 wave grid -> 64m x 32n per wave
  int lm = lane & 15, quad = lane >> 4;
  int m0g = blockIdx.y * 128, n0g = blockIdx.x * 64;
  floatx4 acc[4][2];
  #pragma unroll
  for (int mi = 0; mi < 4; ++mi)
    #pragma unroll
    for (int ni = 0; ni < 2; ++ni)
      acc[mi][ni] = (floatx4)(0.0f);
  int r = t >> 2, seg = (t & 3) * 8;        // 64 rows per round, 4x8 bf16 segs
  const unsigned short* Asrc0 = aeb + (size_t)(m0g + r) * 1024 + seg;
  const unsigned short* Asrc1 = Asrc0 + (size_t)64 * 1024;
  const unsigned short* Bsrc  = w1t + (size_t)(n0g + r) * 1024 + seg;
  unsigned short* Adst0 = At + w * 512;            // wave-uniform bases
  unsigned short* Adst1 = At + 2048 + w * 512;
  unsigned short* Bdst  = Bt + w * 512;
  for (int k0 = 0; k0 < 1024; k0 += 32){
    gl2lds16(Asrc0 + k0, Adst0);
    gl2lds16(Asrc1 + k0, Adst1);
    gl2lds16(Bsrc  + k0, Bdst);
    __syncthreads();
    short8_t a[4], b[2];
    #pragma unroll
    for (int mi = 0; mi < 4; ++mi)
      a[mi] = *(const short8_t*)&At[(wm * 64 + mi * 16 + lm) * 32 + quad * 8];
    #pragma unroll
    for (int ni = 0; ni < 2; ++ni)
      b[ni] = *(const short8_t*)&Bt[(wn * 32 + ni * 16 + lm) * 32 + quad * 8];
    #pragma unroll
    for (int mi = 0; mi < 4; ++mi)
      #pragma unroll
      for (int ni = 0; ni < 2; ++ni)
        acc[mi][ni] = __builtin_amdgcn_mfma_f32_16x16x32_bf16(a[mi], b[ni], acc[mi][ni], 0, 0, 0);
    __syncthreads();
  }
  #pragma unroll
  for (int ni = 0; ni < 2; ++ni){
    int n = n0g + wn * 32 + ni * 16 + lm;
    float b1v = b1[n];
    #pragma unroll
    for (int mi = 0; mi < 4; ++mi){
      int mb = m0g + wm * 64 + mi * 16 + quad * 4;
      #pragma unroll
      for (int rr = 0; rr < 4; ++rr)
        ha[(size_t)(mb + rr) * 1024 + n] = acc[mi][ni][rr] + b1v;
    }
  }
}

// ---------- K3: part[z][b][n] = sum_{d in z-chunk}( gelu(hs+ha)*w2 + sp*ae ) ----------
// grid (128 n-tiles of 32, 2 b-tiles of 32, 8 d-chunks of 128), 256 threads, 2x2/thread
__launch_bounds__(256, 8)
__global__ void k_fused(const float* __restrict__ ha, const float* __restrict__ ae,
                        const float* __restrict__ hs, const float* __restrict__ sp,
                        const float* __restrict__ w2, float* __restrict__ part){
  __shared__ float ha_t[32][34];   // [d][n], pad 34: float2-aligned, <=2-way banks
  __shared__ float ae_t[32][34];
  __shared__ float hs_t[32][34];   // [d][b]
  __shared__ float sp_t[32][34];
  __shared__ float w2_t[32];
  int t = threadIdx.x;
  int n0 = blockIdx.x * 32, b0 = blockIdx.y * 32, dbase = blockIdx.z * 128;
  int row = t >> 3, col4 = (t & 7) * 4;
  int tn2 = (t & 15) * 2, tb2 = (t >> 4) * 2;
  float acc00 = 0.f, acc01 = 0.f, acc10 = 0.f, acc11 = 0.f;   // [b][n]
  for (int dc = 0; dc < 4; ++dc){
    int d0 = dbase + dc * 32;
    float4 v;
    v = *(const float4*)&ha[(size_t)(n0 + row) * 1024 + d0 + col4];
    ha_t[col4+0][row]=v.x; ha_t[col4+1][row]=v.y; ha_t[col4+2][row]=v.z; ha_t[col4+3][row]=v.w;
    v = *(const float4*)&ae[(size_t)(n0 + row) * 1024 + d0 + col4];
    ae_t[col4+0][row]=v.x; ae_t[col4+1][row]=v.y; ae_t[col4+2][row]=v.z; ae_t[col4+3][row]=v.w;
    v = *(const float4*)&hs[(size_t)(b0 + row) * 1024 + d0 + col4];
    hs_t[col4+0][row]=v.x; hs_t[col4+1][row]=v.y; hs_t[col4+2][row]=v.z; hs_t[col4+3][row]=v.w;
    v = *(const float4*)&sp[(size_t)(b0 + row) * 1024 + d0 + col4];
    sp_t[col4+0][row]=v.x; sp_t[col4+1][row]=v.y; sp_t[col4+2][row]=v.z; sp_t[col4+3][row]=v.w;
    if (t < 32) w2_t[t] = w2[d0 + t];
    __syncthreads();
    #pragma unroll 8
    for (int dd = 0; dd < 32; ++dd){
      float2 ha2 = *(const float2*)&ha_t[dd][tn2];
      float2 ae2 = *(const float2*)&ae_t[dd][tn2];
      float2 hs2 = *(const float2*)&hs_t[dd][tb2];
      float2 sp2 = *(const float2*)&sp_t[dd][tb2];
      float wv = w2_t[dd];
      acc00 += gelu_f(hs2.x + ha2.x) * wv + sp2.x * ae2.x;
      acc01 += gelu_f(hs2.x + ha2.y) * wv + sp2.x * ae2.y;
      acc10 += gelu_f(hs2.y + ha2.x) * wv + sp2.y * ae2.x;
      acc11 += gelu_f(hs2.y + ha2.y) * wv + sp2.y * ae2.y;
    }
    __syncthreads();
  }
  float* o = part + (size_t)blockIdx.z * 262144;
  o[(b0 + tb2    ) * 4096 + n0 + tn2    ] = acc00;
  o[(b0 + tb2    ) * 4096 + n0 + tn2 + 1] = acc01;
  o[(b0 + tb2 + 1) * 4096 + n0 + tn2    ] = acc10;
  o[(b0 + tb2 + 1) * 4096 + n0 + tn2 + 1] = acc11;
}

// ---------- K4: sum 8 partials + row softmax ----------
__global__ void k_softmax(const float* __restrict__ part, float* __restrict__ out){
  int b = blockIdx.x, t = threadIdx.x;
  float v[16];
  float m = -3.0e38f;
  #pragma unroll
  for (int i = 0; i < 16; ++i){
    int idx = b * 4096 + t + i * 256;
    float s = 0.f;
    #pragma unroll
    for (int z = 0; z < 8; ++z) s += part[z * 262144 + idx];
    v[i] = s; m = fmaxf(m, s);
  }
  #pragma unroll
  for (int off = 32; off > 0; off >>= 1) m = fmaxf(m, __shfl_xor(m, off, 64));
  __shared__ float redm[4], reds[4];
  int w = t >> 6, lane = t & 63;
  if (lane == 0) redm[w] = m;
  __syncthreads();
  m = fmaxf(fmaxf(redm[0], redm[1]), fmaxf(redm[2], redm[3]));
  float ssum = 0.0f;
  #pragma unroll
  for (int i = 0; i < 16; ++i){
    float e = __builtin_amdgcn_exp2f((v[i] - m) * 1.4426950f);
    v[i] = e; ssum += e;
  }
  #pragma unroll
  for (int off = 32; off > 0; off >>= 1) ssum += __shfl_xor(ssum, off, 64);
  if (lane == 0) reds[w] = ssum;
  __syncthreads();
  ssum = (reds[0] + reds[1]) + (reds[2] + reds[3]);
  float inv = __builtin_amdgcn_rcpf(ssum);
  #pragma unroll
  for (int i = 0; i < 16; ++i) out[b * 4096 + t + i * 256] = v[i] * inv;
}

extern "C" void kernel_launch(void* const* d_in, const int* in_sizes, int n_in,
                              void* d_out, int out_size, void* d_ws, size_t ws_size,
                              hipStream_t stream){
  (void)in_sizes; (void)n_in; (void)out_size; (void)ws_size;
  const float* ms = (const float*)d_in[0];   // [64,1024]
  const float* ae = (const float*)d_in[1];   // [4096,1024]
  const float* bw = (const float*)d_in[2];   // [1024,1024]
  // d_in[3] bilinear_b: softmax-invariant scalar, skipped
  const float* w1 = (const float*)d_in[4];   // [2048,1024]
  const float* b1 = (const float*)d_in[5];   // [1024]
  const float* w2 = (const float*)d_in[6];   // [1024]
  // d_in[7] b2: softmax-invariant scalar, skipped
  float* out = (float*)d_out;

  char* ws = (char*)d_ws;
  float*          sp   = (float*)(ws + 0);          // 256 KB
  float*          hs   = (float*)(ws + 262144);     // 256 KB
  float*          ha   = (float*)(ws + 524288);     // 16 MB
  unsigned short* aeb  = (unsigned short*)(ws + 17301504);  // 8 MB
  float*          part = (float*)(ws + 17301504);   // 8 MB (aliases aeb; aeb dead after k_mfma_ha)
  unsigned short* w1t  = (unsigned short*)(ws + 25690112);  // 2 MB  -> total 26.5 MB

  hipMemsetAsync(sp, 0, 524288, stream);  // zero sp+hs for split-K atomics

  k_cvt_ae    <<<1024, 256, 0, stream>>>(ae, aeb);
  k_trans_w1  <<<dim3(16, 16), 256, 0, stream>>>(w1, w1t);
  k_small_gemm<<<dim3(32, 8), 256, 0, stream>>>(ms, bw, w1, sp, hs);
  k_mfma_ha   <<<dim3(16, 32), 256, 0, stream>>>(aeb, w1t, b1, ha);
  k_fused     <<<dim3(128, 2, 8), 256, 0, stream>>>(ha, ae, hs, sp, w2, part);
  k_softmax   <<<64, 256, 0, stream>>>(part, out);
}